// Round 3
// baseline (542.380 us; speedup 1.0000x reference)
//
#include <hip/hip_runtime.h>
#include <hip/hip_bf16.h>
#include <stdint.h>

typedef __hip_bfloat16 bf16;
typedef __attribute__((ext_vector_type(8))) short short8;   // 8 bf16 = 4 VGPRs
typedef __attribute__((ext_vector_type(4))) short s4v;      // 4 bf16 = 8 B
typedef __attribute__((ext_vector_type(4))) float floatx4;

#define MFMA16(a, b, c) __builtin_amdgcn_mfma_f32_16x16x32_bf16((a), (b), (c), 0, 0, 0)
#define LAMBDA_INIT_F 0.7836057665f   // 0.8 - 0.6*exp(-3.6)
#define FENCE() asm volatile("" ::: "memory")

// async global->LDS, 16B/lane. LDS dest must equal wave-uniform base + lane*16.
__device__ __forceinline__ void async16(const void* g, void* l) {
    __builtin_amdgcn_global_load_lds(
        (const __attribute__((address_space(1))) void*)g,
        (__attribute__((address_space(3))) void*)(uintptr_t)l,
        16, 0, 0);
}

__device__ __forceinline__ float loadf(const void* p, size_t idx, int isbf) {
    if (isbf) return __bfloat162float(((const bf16*)p)[idx]);
    return ((const float*)p)[idx];
}

// ---------------------------------------------------------------------------
// Dtype probe (verified r4): flag[0] = 1 (bf16) / 0 (f32).
// ---------------------------------------------------------------------------
__global__ void detect_dtype(const unsigned short* __restrict__ x, int* __restrict__ flag) {
    const int t = threadIdx.x;
    const unsigned short u = x[2 * t];
    const int e = (u >> 7) & 0xFF;
    int sane = (e >= 110 && e <= 130) ? 1 : 0;
#pragma unroll
    for (int m = 32; m > 0; m >>= 1) sane += __shfl_xor(sane, m);
    if (t == 0) flag[0] = (sane >= 32) ? 1 : 0;
}

// ---------------------------------------------------------------------------
// Elementwise raw-input -> internal bf16 (copy if already bf16). n % 2048 == 0.
// ---------------------------------------------------------------------------
__global__ __launch_bounds__(256) void to_bf16(const void* __restrict__ src,
                                               bf16* __restrict__ dst, int n,
                                               const int* __restrict__ flag,
                                               int skip_if_bf16) {
    if (skip_if_bf16 && flag[0]) return;
    const int i = (blockIdx.x * 256 + threadIdx.x) * 8;
    if (i >= n) return;
    if (flag[0]) {
        *(short8*)(dst + i) = *(const short8*)((const bf16*)src + i);
    } else {
        const float* f = (const float*)src + i;
        short8 r;
#pragma unroll
        for (int j = 0; j < 8; ++j) {
            bf16 h = __float2bfloat16(f[j]);
            r[j] = __builtin_bit_cast(short, h);
        }
        *(short8*)(dst + i) = r;
    }
}

// ---------------------------------------------------------------------------
// 256x256-tile 8-phase pipelined GEMM (m201-template port).
// C[m,n] = sum_k A[m,k]*B[n,k], K=2048, bf16 in.
// 512 threads = 8 waves (2M x 4N), per-wave 128x64 (8x4 16x16 frags).
// BK=64; LDS = 2 dbuf slots x 64 KB; slot = {A0,A1,B0,B1} 16 KB half-tiles.
// 4 phases per K-tile, 16 MFMA each; ONE half-tile staged per phase into a
// region freed by the barrier structure:
//   p0: read A f0-3 + B g0-1, stage A0(t+1)->other slot
//   p1: read B g2-3 + A f4-5, stage A1(t+1)->other
//   p2: read A f6-7,          stage B0(t+2)->current (B reads done at p1)
//   p3:                       stage B1(t+2)->current, s_waitcnt vmcnt(4)
// vmcnt(4) once per tile (before p3's barrier): drains tile t+1's 4 half-
// tiles, leaves B0/B1(t+2)'s 4 loads in flight -- never vmcnt(0) in-loop.
// B frags live in regs across the tile (read once). Swizzle (T2): element
// col-chunk ^= (row&7), realized as inverse-swizzled global source +
// swizzled ds_read addr (rule 21) -- r2-verified 0 bank conflicts.
// T5 setprio around MFMA clusters. Raw s_barrier + asm memory fences.
// Tail: source-clamped unconditional stages keep vmcnt/barrier counts
// uniform; vmcnt(0) after loop so no async LDS write outlives the block.
// Epilogue modes: 1 RoPE+0.125 (Q), 2 RoPE (K), 3 Vt transpose, 4 final.
// ---------------------------------------------------------------------------
__device__ __forceinline__ void gemm256_core(const bf16* __restrict__ A,
                                             const bf16* __restrict__ B,
                                             void* __restrict__ C,
                                             int N, int bm, int bnl,
                                             const int* __restrict__ flag,
                                             const void* __restrict__ fcos,
                                             const void* __restrict__ fsin,
                                             int mode, char* lds) {
    const int K  = 2048;
    const int NT = 32;               // K / 64

    const int tid  = threadIdx.x;
    const int lane = tid & 63;
    const int quad = lane >> 4;
    const int l16  = lane & 15;
    const int w    = tid >> 6;       // 0..7
    const int wr   = w >> 2;         // 0..1 (M half)
    const int wc   = w & 3;          // 0..3 (N quarter)

    // ---- staging geometry: half-tile = 128 rows x 64 k = 16 KB = 2 issues
    // chunk c = i*512 + tid; row = c>>3 (0..127), kc = c&7; source chunk
    // kc ^ (row&7) (inverse swizzle). LDS dest = region + c*16 (linear).
    const int c0 = tid, c1 = tid + 512;
    const int r0 = c0 >> 3, r1 = c1 >> 3;
    const int ks0 = ((c0 & 7) ^ (r0 & 7)) * 8;   // element offset in row
    const int ks1 = ((c1 & 7) ^ (r1 & 7)) * 8;
    const bf16* A0s0 = A + (size_t)(bm * 256 + r0) * K + ks0;
    const bf16* A0s1 = A + (size_t)(bm * 256 + r1) * K + ks1;
    const bf16* A1s0 = A + (size_t)(bm * 256 + 128 + r0) * K + ks0;
    const bf16* A1s1 = A + (size_t)(bm * 256 + 128 + r1) * K + ks1;
    const bf16* B0s0 = B + (size_t)(bnl * 256 + r0) * K + ks0;
    const bf16* B0s1 = B + (size_t)(bnl * 256 + r1) * K + ks1;
    const bf16* B1s0 = B + (size_t)(bnl * 256 + 128 + r0) * K + ks0;
    const bf16* B1s1 = B + (size_t)(bnl * 256 + 128 + r1) * K + ks1;
    const int dst0 = c0 * 16, dst1 = c1 * 16;    // within-region byte offsets

    // ---- read-side swizzled byte offsets (within a slot)
    // frag (row16, kh): byte = region + row*128 + ((kh*4+quad)^(l16&7))*16
    const int swzc  = l16 & 7;
    const int colk0 = ((0 + quad) ^ swzc) * 16;
    const int colk1 = ((4 + quad) ^ swzc) * 16;
    const int aB[2] = { wr * 16384 + l16 * 128 + colk0,
                        wr * 16384 + l16 * 128 + colk1 };
    const int bB[2] = { 32768 + (wc >> 1) * 16384 + ((wc & 1) * 64 + l16) * 128 + colk0,
                        32768 + (wc >> 1) * 16384 + ((wc & 1) * 64 + l16) * 128 + colk1 };

    floatx4 acc[8][4];
#pragma unroll
    for (int f = 0; f < 8; ++f)
#pragma unroll
        for (int g = 0; g < 4; ++g)
#pragma unroll
            for (int r = 0; r < 4; ++r) acc[f][g][r] = 0.0f;

    char* slot0 = lds;
    char* slot1 = lds + 65536;

    // ---- prologue: B0(0),B1(0),A0(0),A1(0),B0(1),B1(1); vmcnt(4) ----
    async16(B0s0, slot0 + 32768 + dst0);  async16(B0s1, slot0 + 32768 + dst1);
    async16(B1s0, slot0 + 49152 + dst0);  async16(B1s1, slot0 + 49152 + dst1);
    async16(A0s0, slot0 + 0     + dst0);  async16(A0s1, slot0 + 0     + dst1);
    async16(A1s0, slot0 + 16384 + dst0);  async16(A1s1, slot0 + 16384 + dst1);
    async16(B0s0 + 64, slot1 + 32768 + dst0);  async16(B0s1 + 64, slot1 + 32768 + dst1);
    async16(B1s0 + 64, slot1 + 49152 + dst0);  async16(B1s1 + 64, slot1 + 49152 + dst1);
    asm volatile("s_waitcnt vmcnt(4)" ::: "memory");
    __builtin_amdgcn_s_barrier();
    FENCE();

    auto tile_body = [&](int tt, char* cur, char* oth) {
        const int t1 = (tt + 1 < NT) ? tt + 1 : NT - 1;   // clamped source tiles
        const int t2 = (tt + 2 < NT) ? tt + 2 : NT - 1;
        const size_t k1 = (size_t)t1 * 64;
        const size_t k2 = (size_t)t2 * 64;

        short8 a03[4][2], a47[4][2], bb[4][2];

        // ---- p0: read A f0-3 (x2kh) + B g0-1; stage A0(t+1)->oth ----
#pragma unroll
        for (int f = 0; f < 4; ++f)
#pragma unroll
            for (int kh = 0; kh < 2; ++kh)
                a03[f][kh] = *(const short8*)(cur + aB[kh] + f * 2048);
#pragma unroll
        for (int g = 0; g < 2; ++g)
#pragma unroll
            for (int kh = 0; kh < 2; ++kh)
                bb[g][kh] = *(const short8*)(cur + bB[kh] + g * 2048);
        async16(A0s0 + k1, oth + 0 + dst0);
        async16(A0s1 + k1, oth + 0 + dst1);
        FENCE();
        __builtin_amdgcn_s_barrier();
        FENCE();
        __builtin_amdgcn_s_setprio(1);
#pragma unroll
        for (int f = 0; f < 4; ++f)
#pragma unroll
            for (int g = 0; g < 2; ++g) {
                acc[f][g] = MFMA16(a03[f][0], bb[g][0], acc[f][g]);
                acc[f][g] = MFMA16(a03[f][1], bb[g][1], acc[f][g]);
            }
        __builtin_amdgcn_s_setprio(0);
        FENCE();
        __builtin_amdgcn_s_barrier();
        FENCE();

        // ---- p1: read B g2-3 + A f4-5; stage A1(t+1)->oth ----
#pragma unroll
        for (int g = 2; g < 4; ++g)
#pragma unroll
            for (int kh = 0; kh < 2; ++kh)
                bb[g][kh] = *(const short8*)(cur + bB[kh] + g * 2048);
#pragma unroll
        for (int f = 0; f < 2; ++f)
#pragma unroll
            for (int kh = 0; kh < 2; ++kh)
                a47[f][kh] = *(const short8*)(cur + aB[kh] + (4 + f) * 2048);
        async16(A1s0 + k1, oth + 16384 + dst0);
        async16(A1s1 + k1, oth + 16384 + dst1);
        FENCE();
        __builtin_amdgcn_s_barrier();
        FENCE();
        __builtin_amdgcn_s_setprio(1);
#pragma unroll
        for (int f = 0; f < 4; ++f)
#pragma unroll
            for (int g = 2; g < 4; ++g) {
                acc[f][g] = MFMA16(a03[f][0], bb[g][0], acc[f][g]);
                acc[f][g] = MFMA16(a03[f][1], bb[g][1], acc[f][g]);
            }
        __builtin_amdgcn_s_setprio(0);
        FENCE();
        __builtin_amdgcn_s_barrier();
        FENCE();

        // ---- p2: read A f6-7; stage B0(t+2)->cur (B reads finished p1) ----
#pragma unroll
        for (int f = 2; f < 4; ++f)
#pragma unroll
            for (int kh = 0; kh < 2; ++kh)
                a47[f][kh] = *(const short8*)(cur + aB[kh] + (4 + f) * 2048);
        async16(B0s0 + k2, cur + 32768 + dst0);
        async16(B0s1 + k2, cur + 32768 + dst1);
        FENCE();
        __builtin_amdgcn_s_barrier();
        FENCE();
        __builtin_amdgcn_s_setprio(1);
#pragma unroll
        for (int f = 0; f < 4; ++f)
#pragma unroll
            for (int g = 0; g < 2; ++g) {
                acc[4 + f][g] = MFMA16(a47[f][0], bb[g][0], acc[4 + f][g]);
                acc[4 + f][g] = MFMA16(a47[f][1], bb[g][1], acc[4 + f][g]);
            }
        __builtin_amdgcn_s_setprio(0);
        FENCE();
        __builtin_amdgcn_s_barrier();
        FENCE();

        // ---- p3: stage B1(t+2)->cur; vmcnt(4) = tile t+1 fully landed ----
        async16(B1s0 + k2, cur + 49152 + dst0);
        async16(B1s1 + k2, cur + 49152 + dst1);
        asm volatile("s_waitcnt vmcnt(4)" ::: "memory");
        __builtin_amdgcn_s_barrier();
        FENCE();
        __builtin_amdgcn_s_setprio(1);
#pragma unroll
        for (int f = 0; f < 4; ++f)
#pragma unroll
            for (int g = 2; g < 4; ++g) {
                acc[4 + f][g] = MFMA16(a47[f][0], bb[g][0], acc[4 + f][g]);
                acc[4 + f][g] = MFMA16(a47[f][1], bb[g][1], acc[4 + f][g]);
            }
        __builtin_amdgcn_s_setprio(0);
        FENCE();
        __builtin_amdgcn_s_barrier();
        FENCE();
    };

    for (int u = 0; u < NT; u += 2) {
        tile_body(u,     slot0, slot1);
        tile_body(u + 1, slot1, slot0);
    }
    asm volatile("s_waitcnt vmcnt(0)" ::: "memory");
    FENCE();

    // ---- epilogue (C/D layout: col=l16, row=quad*4+r) ----
    const int isbf  = flag[0];
    const int mbase = bm * 256 + wr * 128;
    const int nbase = bnl * 256 + wc * 64;
    if (mode == 3) {
        // Vt write: lane n fixed, 4 consecutive s -> one 8B store
#pragma unroll
        for (int f = 0; f < 8; ++f)
#pragma unroll
            for (int g = 0; g < 4; ++g) {
                const int n  = nbase + g * 16 + l16;
                const int m0 = mbase + f * 16 + quad * 4;
                const int bb2 = m0 >> 11;
                const int s0 = m0 & 2047;
                s4v pk;
#pragma unroll
                for (int r = 0; r < 4; ++r) {
                    bf16 hv = __float2bfloat16(acc[f][g][r]);
                    pk[r] = __builtin_bit_cast(short, hv);
                }
                *(s4v*)((bf16*)C + ((size_t)(bb2 * 2048 + n)) * 2048 + s0) = pk;
            }
    } else if (mode == 1 || mode == 2) {
        const float qs = (mode == 1) ? 0.125f : 1.0f;
#pragma unroll
        for (int f = 0; f < 8; ++f)
#pragma unroll
            for (int g = 0; g < 4; ++g) {
                const int n   = nbase + g * 16 + l16;
                const int jp  = (n & 63) >> 1;                 // rope pair index
                const float sg = (n & 1) ? 1.0f : -1.0f;       // even: re, odd: im
#pragma unroll
                for (int r = 0; r < 4; ++r) {
                    const int m = mbase + f * 16 + quad * 4 + r;
                    const int s = m & 2047;
                    const float v  = acc[f][g][r];
                    const float pv = __shfl_xor(v, 1);         // partner (n^1), same m
                    const float ct = loadf(fcos, (size_t)s * 32 + jp, isbf);
                    const float st = loadf(fsin, (size_t)s * 32 + jp, isbf);
                    const float out = (v * ct + sg * pv * st) * qs;
                    ((bf16*)C)[(size_t)m * N + n] = __float2bfloat16(out);
                }
            }
    } else {
        const int c_bf = (mode == 4) ? isbf : 1;
#pragma unroll
        for (int f = 0; f < 8; ++f)
#pragma unroll
            for (int g = 0; g < 4; ++g) {
                const int n = nbase + g * 16 + l16;
#pragma unroll
                for (int r = 0; r < 4; ++r) {
                    const int m = mbase + f * 16 + quad * 4 + r;
                    if (c_bf) ((bf16*)C)[(size_t)m * N + n] = __float2bfloat16(acc[f][g][r]);
                    else      ((float*)C)[(size_t)m * N + n] = acc[f][g][r];
                }
            }
    }
}

// Fused QKV: grid (24,16); bx>>3 selects weight/epilogue (block-uniform).
__global__ __launch_bounds__(512, 2) void gemm256_qkv(const bf16* __restrict__ A,
                                                      const bf16* __restrict__ Wq_s,
                                                      const bf16* __restrict__ Wk_s,
                                                      const bf16* __restrict__ Wv_s,
                                                      const void* __restrict__ WqR,
                                                      const void* __restrict__ WkR,
                                                      const void* __restrict__ WvR,
                                                      bf16* __restrict__ qbuf,
                                                      bf16* __restrict__ kbuf,
                                                      bf16* __restrict__ vtbuf,
                                                      const int* __restrict__ flag,
                                                      const void* __restrict__ fcos,
                                                      const void* __restrict__ fsin) {
    extern __shared__ char lds[];
    const int wsel = blockIdx.x >> 3;
    const int bnl  = blockIdx.x & 7;
    const int isbf = flag[0];
    const bf16* Bp;
    void* Cp;
    int mode;
    if (wsel == 0)      { Bp = isbf ? (const bf16*)WqR : Wq_s; Cp = qbuf;  mode = 1; }
    else if (wsel == 1) { Bp = isbf ? (const bf16*)WkR : Wk_s; Cp = kbuf;  mode = 2; }
    else                { Bp = isbf ? (const bf16*)WvR : Wv_s; Cp = vtbuf; mode = 3; }
    gemm256_core(A, Bp, Cp, 2048, blockIdx.y, bnl, flag, fcos, fsin, mode, lds);
}

// Plain/final GEMM: grid (N/256, M/256).
__global__ __launch_bounds__(512, 2) void gemm256_ep(const bf16* __restrict__ A,
                                                     const bf16* __restrict__ B,
                                                     void* __restrict__ C,
                                                     int N,
                                                     const int* __restrict__ flag,
                                                     int mode) {
    extern __shared__ char lds[];
    gemm256_core(A, B, C, N, blockIdx.y, blockIdx.x, flag, nullptr, nullptr, mode, lds);
}

// ---------------------------------------------------------------------------
__global__ void lambda_kernel(const void* lq1, const void* lq2,
                              const void* lk1, const void* lk2,
                              float* out, const int* __restrict__ flag) {
    const int isbf = flag[0];
    const int t = threadIdx.x;
    float p1 = loadf(lq1, t, isbf) * loadf(lk1, t, isbf);
    float p2 = loadf(lq2, t, isbf) * loadf(lk2, t, isbf);
#pragma unroll
    for (int m = 32; m > 0; m >>= 1) {
        p1 += __shfl_xor(p1, m);
        p2 += __shfl_xor(p2, m);
    }
    if (t == 0) out[0] = expf(p1) - expf(p2) + LAMBDA_INIT_F;
}

// ---------------------------------------------------------------------------
// Differential flash attention, paired-tile blocks, max-free softmax
// (r7-verified). XCD-aware block swizzle.
// grid = 512 blocks; block does q-tiles p and 31-p (33 iters).
// ---------------------------------------------------------------------------
__global__ __launch_bounds__(256) void diff_attn(const bf16* __restrict__ Q,
                                                 const bf16* __restrict__ K,
                                                 const bf16* __restrict__ Vt,
                                                 bf16* __restrict__ ctx,
                                                 const float* __restrict__ lam,
                                                 const void* __restrict__ norm_w,
                                                 const int* __restrict__ flag) {
    __shared__ __align__(16) char smem[55296];
    bf16* K1s = (bf16*)smem;                 // 64 keys x 64 dims  (8 KB) swizzled
    bf16* K2s = (bf16*)(smem + 8192);        // 8 KB swizzled
    bf16* Vs  = (bf16*)(smem + 16384);       // 128 dims x 64 keys (16 KB) swizzled
    char* pool = smem + 32768;               // 22528 B: Q staging / P1,P2

    const int isbf = flag[0];
    const int tid  = threadIdx.x;
    const int lane = tid & 63;
    const int quad = lane >> 4;
    const int l16  = lane & 15;
    const int w    = tid >> 6;
    const int t7   = l16 & 7;

    const int bidx = blockIdx.x;
    const int c8   = bidx & 7;               // presumed XCD (round-robin)
    const int r6   = bidx >> 3;
    const int p    = r6 & 15;                // pair id: tiles p and 31-p
    const int grp  = (r6 >> 4) * 8 + c8;     // (b,h) group; 4 groups per XCD
    const int h    = grp & 15;
    const int b    = grp >> 4;

    const float lambda_full = lam[0];
    float nw[8];
#pragma unroll
    for (int j = 0; j < 8; ++j) nw[j] = loadf(norm_w, j * 16 + l16, isbf);

    // P staging: per-wave 16 rows x stride 88 bf16 (176 B)
    bf16* P1s = (bf16*)(pool + w * 2816);
    bf16* P2s = (bf16*)(pool + 11264 + w * 2816);

    for (int tsel = 0; tsel < 2; ++tsel) {
        const int qt = tsel ? (31 - p) : p;
        const int q0 = qt * 64;

        __syncthreads();   // pool (P region of prev tile) free for Q staging

        // ---- Q staging via async16, swizzled; both heads (16 KB of pool) ----
#pragma unroll
        for (int i = 0; i < 2; ++i) {
            const int c = i * 256 + tid;     // 512 chunks (64 rows x 8)
            const int row = c >> 3, cc = c & 7;
            const int inner = cc ^ (row & 7);
            async16(Q + ((size_t)(b * 2048 + q0 + row) * 32 + 2 * h) * 64 + inner * 8,
                    pool + c * 16);
            async16(Q + ((size_t)(b * 2048 + q0 + row) * 32 + 2 * h + 1) * 64 + inner * 8,
                    pool + 8192 + c * 16);
        }
        __syncthreads();

        short8 qf1[2], qf2[2];
        {
            const int rho = w * 16 + l16;    // rho&7 == t7
#pragma unroll
            for (int c = 0; c < 2; ++c) {
                const int ch = (c * 4 + quad) ^ t7;
                qf1[c] = *(const short8*)(pool + rho * 128 + ch * 16);
                qf2[c] = *(const short8*)(pool + 8192 + rho * 128 + ch * 16);
            }
        }

        floatx4 O1[8], O2[8];
#pragma unroll
        for (int j = 0; j < 8; ++j)
#pragma unroll
            for (int r = 0; r < 4; ++r) { O1[j][r] = 0.0f; O2[j][r] = 0.0f; }
        float lp1[4] = {0.f, 0.f, 0.f, 0.f};
        float lp2[4] = {0.f, 0.f, 0.f, 0.f};

        for (int kt0 = 0; kt0 <= q0; kt0 += 64) {
            __syncthreads();   // (A) prev iter's LDS reads done
#pragma unroll
            for (int i = 0; i < 2; ++i) {
                const int c = i * 256 + tid;
                const int row = c >> 3, cc = c & 7;
                const int inner = cc ^ (row & 7);
                async16(K + ((size_t)(b * 2048 + kt0 + row) * 32 + 2 * h) * 64 + inner * 8,
                        (char*)K1s + c * 16);
                async16(K + ((size_t)(b * 2048 + kt0 + row) * 32 + 2 * h + 1) * 64 + inner * 8,
                        (char*)K2s + c * 16);
            }
#pragma unroll
            for (int i = 0; i < 4; ++i) {
                const int c = i * 256 + tid;     // 1024 chunks (128 dims x 8)
                const int d = c >> 3, cc = c & 7;
                const int inner = cc ^ (d & 7);
                async16(Vt + ((size_t)(b * 16 + h) * 128 + d) * 2048 + kt0 + inner * 8,
                        (char*)Vs + c * 16);
            }
            __syncthreads();   // (B) staging visible

            // ---- scores: wave's 16 q-rows x 64 keys, both heads ----
            floatx4 s1[4], s2[4];
#pragma unroll
            for (int j = 0; j < 4; ++j)
#pragma unroll
                for (int r = 0; r < 4; ++r) { s1[j][r] = 0.0f; s2[j][r] = 0.0f; }
#pragma unroll
            for (int c = 0; c < 2; ++c) {
                const int ch = ((c * 4 + quad) ^ t7) * 16;
#pragma unroll
                for (int j = 0; j < 4; ++j) {
                    short8 k1f = *(const short8*)((const char*)K1s + (j * 16 + l16) * 128 + ch);
                    s1[j] = MFMA16(qf1[c], k1f, s1[j]);
                    short8 k2f = *(const short8*)((const char*)K2s + (j * 16 + l16) * 128 + ch);
                    s2[j] = MFMA16(qf2[c], k2f, s2[j]);
                }
            }

            if (kt0 == q0) {   // diagonal tile mask
#pragma unroll
                for (int j = 0; j < 4; ++j)
#pragma unroll
                    for (int r = 0; r < 4; ++r)
                        if (j * 16 + l16 > w * 16 + quad * 4 + r) {
                            s1[j][r] = -1e30f;
                            s2[j][r] = -1e30f;
                        }
            }

            // ---- exp + per-lane row-sum partials + P write (no shuffles) ----
#pragma unroll
            for (int j = 0; j < 4; ++j)
#pragma unroll
                for (int r = 0; r < 4; ++r) {
                    const float e1 = __expf(s1[j][r]);
                    const float e2 = __expf(s2[j][r]);
                    lp1[r] += e1;
                    lp2[r] += e2;
                    P1s[(quad * 4 + r) * 88 + j * 16 + l16] = __float2bfloat16(e1);
                    P2s[(quad * 4 + r) * 88 + j * 16 + l16] = __float2bfloat16(e2);
                }
            // P is per-wave-private: same-wave ds ordering suffices, no barrier.

            // ---- PV: O[16 x 128] += P @ V ----
#pragma unroll
            for (int c = 0; c < 2; ++c) {
                short8 a1 = *(const short8*)((const char*)P1s + l16 * 176 + c * 64 + quad * 16);
                short8 a2 = *(const short8*)((const char*)P2s + l16 * 176 + c * 64 + quad * 16);
                const int ch = ((c * 4 + quad) ^ t7) * 16;
#pragma unroll
                for (int j = 0; j < 8; ++j) {
                    short8 vb = *(const short8*)((const char*)Vs + (j * 16 + l16) * 128 + ch);
                    O1[j] = MFMA16(a1, vb, O1[j]);
                    O2[j] = MFMA16(a2, vb, O2[j]);
                }
            }
        }

        // ---- epilogue: reduce row sums once, diff, RMSNorm, norm_w, store ----
#pragma unroll
        for (int r = 0; r < 4; ++r) {
            float t1 = lp1[r], t2 = lp2[r];
            t1 += __shfl_xor(t1, 1); t2 += __shfl_xor(t2, 1);
            t1 += __shfl_xor(t1, 2); t2 += __shfl_xor(t2, 2);
            t1 += __shfl_xor(t1, 4); t2 += __shfl_xor(t2, 4);
            t1 += __shfl_xor(t1, 8); t2 += __shfl_xor(t2, 8);
            const float i1 = 1.0f / t1;
            const float i2 = lambda_full / t2;
            float cv[8];
            float ss = 0.0f;
#pragma unroll
            for (int j = 0; j < 8; ++j) {
                const float v = O1[j][r] * i1 - O2[j][r] * i2;
                cv[j] = v;
                ss += v * v;
            }
            ss += __shfl_xor(ss, 1);
            ss += __shfl_xor(ss, 2);
            ss += __shfl_xor(ss, 4);
            ss += __shfl_xor(ss, 8);
            const float scale = rsqrtf(ss * (1.0f / 128.0f) + 1e-5f);
            const int row = q0 + w * 16 + quad * 4 + r;
            const size_t base = ((size_t)(b * 2048) + row) * 2048 + h * 128;
#pragma unroll
            for (int j = 0; j < 8; ++j)
                ctx[base + j * 16 + l16] = __float2bfloat16(cv[j] * scale * nw[j]);
        }
    }
}

// ---------------------------------------------------------------------------
extern "C" void kernel_launch(void* const* d_in, const int* in_sizes, int n_in,
                              void* d_out, int out_size, void* d_ws, size_t ws_size,
                              hipStream_t stream) {
    const void* x   = d_in[0];
    const void* Wq  = d_in[1];
    const void* Wk  = d_in[2];
    const void* Wv  = d_in[3];
    const void* Wo  = d_in[4];
    const void* lq1 = d_in[5];
    const void* lq2 = d_in[6];
    const void* lk1 = d_in[7];
    const void* lk2 = d_in[8];
    const void* nw  = d_in[9];
    const void* fc  = d_in[10];
    const void* fs  = d_in[11];

    const size_t BUF = (size_t)4096 * 2048 * sizeof(bf16);   // 16 MiB
    if (ws_size < 4 * BUF + 64) return;
    char* ws = (char*)d_ws;
    bf16*  qbuf  = (bf16*)(ws);
    bf16*  kbuf  = (bf16*)(ws + BUF);
    bf16*  vbuf  = (bf16*)(ws + 2 * BUF);    // xb, then ctxb (xb dead after QKV GEMM)
    bf16*  vtbuf = (bf16*)(ws + 3 * BUF);    // written directly by V part (mode 3)
    float* lamb  = (float*)(ws + 4 * BUF);
    int*   flag  = (int*)(ws + 4 * BUF + 8);
    bf16*  xb    = vbuf;
    bf16*  ctxb  = vbuf;

    // Weight staging for the f32 path: all three converted weights live in
    // d_out simultaneously (24 MiB <= 32 MiB f32 output; bf16 path skips
    // staging and reads the original tensors in place).
    bf16* wq_s = (bf16*)d_out;
    bf16* wk_s = wq_s + (size_t)2048 * 2048;
    bf16* wv_s = wk_s + (size_t)2048 * 2048;

    const int NX = 2 * 2048 * 2048;
    const int NW = 2048 * 2048;

    // allow 128 KiB dynamic LDS for the pipelined GEMMs (idempotent host call)
    hipFuncSetAttribute(reinterpret_cast<const void*>(gemm256_qkv),
                        hipFuncAttributeMaxDynamicSharedMemorySize, 131072);
    hipFuncSetAttribute(reinterpret_cast<const void*>(gemm256_ep),
                        hipFuncAttributeMaxDynamicSharedMemorySize, 131072);

    detect_dtype<<<1, 64, 0, stream>>>((const unsigned short*)x, flag);
    to_bf16<<<NX / 2048, 256, 0, stream>>>(x, xb, NX, flag, 0);

    to_bf16<<<NW / 2048, 256, 0, stream>>>(Wq, wq_s, NW, flag, 1);
    to_bf16<<<NW / 2048, 256, 0, stream>>>(Wk, wk_s, NW, flag, 1);
    to_bf16<<<NW / 2048, 256, 0, stream>>>(Wv, wv_s, NW, flag, 1);

    dim3 gq(24, 16);   // (3*2048)/256, 4096/256 — fused QKV
    gemm256_qkv<<<gq, 512, 131072, stream>>>(xb, wq_s, wk_s, wv_s, Wq, Wk, Wv,
                                             qbuf, kbuf, vtbuf, flag, fc, fs);

    lambda_kernel<<<1, 64, 0, stream>>>(lq1, lq2, lk1, lk2, lamb, flag);

    diff_attn<<<512, 256, 0, stream>>>(qbuf, kbuf, vtbuf, ctxb, lamb, nw, flag);

    to_bf16<<<NW / 2048, 256, 0, stream>>>(Wo, qbuf, NW, flag, 0);   // qbuf dead after attn
    dim3 gf(8, 16);    // 2048/256, 4096/256
    gemm256_ep<<<gf, 512, 131072, stream>>>(ctxb, qbuf, d_out, 2048, flag, 4);
}

// Round 4
// 465.629 us; speedup vs baseline: 1.1648x; 1.1648x over previous
//
#include <hip/hip_runtime.h>
#include <hip/hip_bf16.h>
#include <stdint.h>

typedef __hip_bfloat16 bf16;
typedef __attribute__((ext_vector_type(8))) short short8;   // 8 bf16 = 4 VGPRs
typedef __attribute__((ext_vector_type(4))) short s4v;      // 4 bf16 = 8 B
typedef __attribute__((ext_vector_type(4))) float floatx4;

#define MFMA16(a, b, c) __builtin_amdgcn_mfma_f32_16x16x32_bf16((a), (b), (c), 0, 0, 0)
#define LAMBDA_INIT_F 0.7836057665f   // 0.8 - 0.6*exp(-3.6)
#define FENCE() asm volatile("" ::: "memory")

// async global->LDS, 16B/lane. LDS dest must equal wave-uniform base + lane*16.
__device__ __forceinline__ void async16(const void* g, void* l) {
    __builtin_amdgcn_global_load_lds(
        (const __attribute__((address_space(1))) void*)g,
        (__attribute__((address_space(3))) void*)(uintptr_t)l,
        16, 0, 0);
}

__device__ __forceinline__ float loadf(const void* p, size_t idx, int isbf) {
    if (isbf) return __bfloat162float(((const bf16*)p)[idx]);
    return ((const float*)p)[idx];
}

// ---------------------------------------------------------------------------
// Dtype probe (verified r4): flag[0] = 1 (bf16) / 0 (f32).
// ---------------------------------------------------------------------------
__global__ void detect_dtype(const unsigned short* __restrict__ x, int* __restrict__ flag) {
    const int t = threadIdx.x;
    const unsigned short u = x[2 * t];
    const int e = (u >> 7) & 0xFF;
    int sane = (e >= 110 && e <= 130) ? 1 : 0;
#pragma unroll
    for (int m = 32; m > 0; m >>= 1) sane += __shfl_xor(sane, m);
    if (t == 0) flag[0] = (sane >= 32) ? 1 : 0;
}

__device__ __forceinline__ void conv_body(const void* src, bf16* dst, int boff,
                                          int isbf) {
    const int i = (boff * 256 + threadIdx.x) * 8;
    if (isbf) {
        *(short8*)(dst + i) = *(const short8*)((const bf16*)src + i);
    } else {
        const float* f = (const float*)src + i;
        short8 r;
#pragma unroll
        for (int j = 0; j < 8; ++j) {
            bf16 h = __float2bfloat16(f[j]);
            r[j] = __builtin_bit_cast(short, h);
        }
        *(short8*)(dst + i) = r;
    }
}

// ---------------------------------------------------------------------------
// Fused conversion of x + Wq + Wk + Wv (one launch instead of four).
// Weight staging skipped in the bf16 path (consumed in place by the GEMM).
// grid = 4096 (x) + 3*2048 (weights) = 10240 blocks.
// ---------------------------------------------------------------------------
__global__ __launch_bounds__(256) void convert_all(const void* __restrict__ x,
                                                   const void* __restrict__ Wq,
                                                   const void* __restrict__ Wk,
                                                   const void* __restrict__ Wv,
                                                   bf16* __restrict__ xb,
                                                   bf16* __restrict__ wq,
                                                   bf16* __restrict__ wk,
                                                   bf16* __restrict__ wv,
                                                   const int* __restrict__ flag) {
    const int bid  = blockIdx.x;
    const int isbf = flag[0];
    if (bid < 4096)      { conv_body(x, xb, bid, isbf); }
    else if (bid < 6144) { if (isbf) return; conv_body(Wq, wq, bid - 4096, 0); }
    else if (bid < 8192) { if (isbf) return; conv_body(Wk, wk, bid - 6144, 0); }
    else                 { if (isbf) return; conv_body(Wv, wv, bid - 8192, 0); }
}

// Single-tensor convert (Wo, after attn frees qbuf).
__global__ __launch_bounds__(256) void to_bf16(const void* __restrict__ src,
                                               bf16* __restrict__ dst, int n,
                                               const int* __restrict__ flag,
                                               int skip_if_bf16) {
    if (skip_if_bf16 && flag[0]) return;
    const int i = (blockIdx.x * 256 + threadIdx.x) * 8;
    if (i >= n) return;
    conv_body(src, dst, blockIdx.x, flag[0]);
}

// ---------------------------------------------------------------------------
// 256xBNT-tile pipelined GEMM core (r2-verified structure, now templated on
// the N tile size). C[m,n] = sum_k A[m,k]*B[n,k], K=2048, bf16 in.
// 512 threads = 8 waves. BNT=256: waves 2Mx4N, per-wave 128x64 (8x4 frags).
// BNT=128: waves 4Mx2N, per-wave 64x64 (4x4 frags) -- parameter change only,
// identical ring/barrier/vmcnt structure.
// BK=32; 4-slot LDS ring (4 x SLOT); staging runs 2 tiles ahead of compute
// (mod-4 separation 2 -> writer/reader never collide). Counted vmcnt once
// per tile: drains tile t+1's loads, leaves t+2's in flight (3 or 4 per
// thread per tile) -- never vmcnt(0) in the main loop. Raw s_barrier +
// empty-asm fences. T2 swizzle: element chunk ^= ((row>>3)&1)<<1 on the
// global source + swizzled ds_read addr (r2-verified 0 bank conflicts).
// T5 setprio around MFMA clusters.
// Epilogue modes: 1 RoPE+0.125 (Q), 2 RoPE (K), 3 Vt transpose, 4 final.
// ---------------------------------------------------------------------------
template <int BNT>
__device__ __forceinline__ void gemm_core256(const bf16* __restrict__ A,
                                             const bf16* __restrict__ B,
                                             void* __restrict__ C,
                                             int N, int bm, int bnl,
                                             const int* __restrict__ flag,
                                             const void* __restrict__ fcos,
                                             const void* __restrict__ fsin,
                                             int mode, char* lds) {
    constexpr int K    = 2048;
    constexpr int NT   = 64;                 // K / 32
    constexpr int ASZ  = 16384;              // 256 rows * 32k * 2B
    constexpr int BSZ  = BNT * 64;           // BNT rows * 32k * 2B
    constexpr int SLOT = ASZ + BSZ;
    constexpr int F    = (BNT == 256) ? 8 : 4;   // M frags per wave
    constexpr int FH   = F / 2;
    constexpr int BCH  = BNT / 128;          // per-thread B staging chunks

    const int tid  = threadIdx.x;
    const int lane = tid & 63;
    const int quad = lane >> 4;
    const int l16  = lane & 15;
    const int w    = tid >> 6;
    const int wr   = (BNT == 256) ? (w >> 2) : (w >> 1);
    const int wc   = (BNT == 256) ? (w & 3) : (w & 1);

    // ---- staging: chunk c: row = c>>2, kc = c&3; inverse-swizzled source
    const int c0 = tid, c1 = tid + 512;
    const int r0 = c0 >> 2, r1 = c1 >> 2;
    const int kc0 = (c0 & 3) ^ (((r0 >> 3) & 1) << 1);
    const int kc1 = (c1 & 3) ^ (((r1 >> 3) & 1) << 1);
    const bf16* Asrc0 = A + (size_t)(bm * 256 + r0) * K + kc0 * 8;
    const bf16* Asrc1 = A + (size_t)(bm * 256 + r1) * K + kc1 * 8;
    const bf16* Bsrc0 = B + (size_t)(bnl * BNT + r0) * K + kc0 * 8;
    const bf16* Bsrc1 = B + (size_t)(bnl * BNT + r1) * K + kc1 * 8;   // BCH==2 only
    const int dA0 = c0 * 16, dA1 = c1 * 16;
    const int dB0 = ASZ + c0 * 16, dB1 = ASZ + c1 * 16;

    // ---- read-side swizzled byte offsets within a slot
    const int swz = (quad * 16) ^ ((l16 & 8) << 2);
    int offA[8], offB[4];
#pragma unroll
    for (int f = 0; f < F; ++f) offA[f] = (wr * (F * 16) + f * 16 + l16) * 64 + swz;
#pragma unroll
    for (int g = 0; g < 4; ++g) offB[g] = ASZ + (wc * 64 + g * 16 + l16) * 64 + swz;

    floatx4 acc[F][4];
#pragma unroll
    for (int f = 0; f < F; ++f)
#pragma unroll
        for (int g = 0; g < 4; ++g)
#pragma unroll
            for (int r = 0; r < 4; ++r) acc[f][g][r] = 0.0f;

    // ---- prologue: stage tiles 0 and 1; wait tile 0 (leave tile 1 in flight)
#pragma unroll
    for (int ts = 0; ts < 2; ++ts) {
        char* slot = lds + ts * SLOT;
        async16(Asrc0 + ts * 32, slot + dA0);
        async16(Asrc1 + ts * 32, slot + dA1);
        async16(Bsrc0 + ts * 32, slot + dB0);
        if constexpr (BCH == 2) async16(Bsrc1 + ts * 32, slot + dB1);
    }
    if constexpr (BNT == 256) asm volatile("s_waitcnt vmcnt(4)" ::: "memory");
    else                      asm volatile("s_waitcnt vmcnt(3)" ::: "memory");
    __builtin_amdgcn_s_barrier();
    FENCE();

    // ---- main loop: 2 phases per K-tile (r2-verified structure)
#pragma unroll 4
    for (int t = 0; t < NT; ++t) {
        char* slot  = lds + (t & 3) * SLOT;
        const int ts = t + 2;
        char* wslot = lds + (ts & 3) * SLOT;

        // phase 0: read A first-half + all B, stage A(t+2)
        short8 af[FH], bfv[4];
#pragma unroll
        for (int f = 0; f < FH; ++f) af[f] = *(const short8*)(slot + offA[f]);
#pragma unroll
        for (int g = 0; g < 4; ++g) bfv[g] = *(const short8*)(slot + offB[g]);
        if (ts < NT) {
            async16(Asrc0 + (size_t)ts * 32, wslot + dA0);
            async16(Asrc1 + (size_t)ts * 32, wslot + dA1);
        }
        FENCE();
        __builtin_amdgcn_s_barrier();
        FENCE();
        __builtin_amdgcn_s_setprio(1);
#pragma unroll
        for (int f = 0; f < FH; ++f)
#pragma unroll
            for (int g = 0; g < 4; ++g)
                acc[f][g] = MFMA16(af[f], bfv[g], acc[f][g]);
        __builtin_amdgcn_s_setprio(0);

        // phase 1: read A second-half (B reused), stage B(t+2), counted vmcnt
        short8 af2[FH];
#pragma unroll
        for (int f = 0; f < FH; ++f) af2[f] = *(const short8*)(slot + offA[FH + f]);
        if (ts < NT) {
            async16(Bsrc0 + (size_t)ts * 32, wslot + dB0);
            if constexpr (BCH == 2) async16(Bsrc1 + (size_t)ts * 32, wslot + dB1);
            if constexpr (BNT == 256) asm volatile("s_waitcnt vmcnt(4)" ::: "memory");
            else                      asm volatile("s_waitcnt vmcnt(3)" ::: "memory");
        } else {
            asm volatile("s_waitcnt vmcnt(0)" ::: "memory");
        }
        __builtin_amdgcn_s_barrier();
        FENCE();
        __builtin_amdgcn_s_setprio(1);
#pragma unroll
        for (int f = 0; f < FH; ++f)
#pragma unroll
            for (int g = 0; g < 4; ++g)
                acc[FH + f][g] = MFMA16(af2[f], bfv[g], acc[FH + f][g]);
        __builtin_amdgcn_s_setprio(0);
    }

    // ---- epilogue (C/D layout: col=l16, row=quad*4+r) ----
    const int isbf  = flag[0];
    const int mbase = bm * 256 + wr * (F * 16);
    const int nbase = bnl * BNT + wc * 64;
    if (mode == 3) {
        // Vt write: lane n fixed, 4 consecutive s -> one 8B store
#pragma unroll
        for (int f = 0; f < F; ++f)
#pragma unroll
            for (int g = 0; g < 4; ++g) {
                const int n  = nbase + g * 16 + l16;
                const int m0 = mbase + f * 16 + quad * 4;
                const int bb2 = m0 >> 11;
                const int s0 = m0 & 2047;
                s4v pk;
#pragma unroll
                for (int r = 0; r < 4; ++r) {
                    bf16 hv = __float2bfloat16(acc[f][g][r]);
                    pk[r] = __builtin_bit_cast(short, hv);
                }
                *(s4v*)((bf16*)C + ((size_t)(bb2 * 2048 + n)) * 2048 + s0) = pk;
            }
    } else if (mode == 1 || mode == 2) {
        const float qs = (mode == 1) ? 0.125f : 1.0f;
#pragma unroll
        for (int f = 0; f < F; ++f)
#pragma unroll
            for (int g = 0; g < 4; ++g) {
                const int n   = nbase + g * 16 + l16;
                const int jp  = (n & 63) >> 1;                 // rope pair index
                const float sg = (n & 1) ? 1.0f : -1.0f;       // even: re, odd: im
#pragma unroll
                for (int r = 0; r < 4; ++r) {
                    const int m = mbase + f * 16 + quad * 4 + r;
                    const int s = m & 2047;
                    const float v  = acc[f][g][r];
                    const float pv = __shfl_xor(v, 1);         // partner (n^1), same m
                    const float ct = loadf(fcos, (size_t)s * 32 + jp, isbf);
                    const float st = loadf(fsin, (size_t)s * 32 + jp, isbf);
                    const float out = (v * ct + sg * pv * st) * qs;
                    ((bf16*)C)[(size_t)m * N + n] = __float2bfloat16(out);
                }
            }
    } else {
        const int c_bf = (mode == 4) ? isbf : 1;
#pragma unroll
        for (int f = 0; f < F; ++f)
#pragma unroll
            for (int g = 0; g < 4; ++g) {
                const int n = nbase + g * 16 + l16;
#pragma unroll
                for (int r = 0; r < 4; ++r) {
                    const int m = mbase + f * 16 + quad * 4 + r;
                    if (c_bf) ((bf16*)C)[(size_t)m * N + n] = __float2bfloat16(acc[f][g][r]);
                    else      ((float*)C)[(size_t)m * N + n] = acc[f][g][r];
                }
            }
    }
}

// Fused QKV: grid (24,16) = 384 blocks. Bijective XCD swizzle (384%8==0):
// flat%8 = XCD under round-robin dispatch -> each XCD owns 48 contiguous
// tiles in (wsel, bm-major) order, so co-resident blocks share A/B panels.
__global__ __launch_bounds__(512, 2) void gemm256_qkv(const bf16* __restrict__ A,
                                                      const bf16* __restrict__ Wq_s,
                                                      const bf16* __restrict__ Wk_s,
                                                      const bf16* __restrict__ Wv_s,
                                                      const void* __restrict__ WqR,
                                                      const void* __restrict__ WkR,
                                                      const void* __restrict__ WvR,
                                                      bf16* __restrict__ qbuf,
                                                      bf16* __restrict__ kbuf,
                                                      bf16* __restrict__ vtbuf,
                                                      const int* __restrict__ flag,
                                                      const void* __restrict__ fcos,
                                                      const void* __restrict__ fsin) {
    extern __shared__ char lds[];
    const int flat = blockIdx.y * 24 + blockIdx.x;
    const int swz  = (flat & 7) * 48 + (flat >> 3);
    const int wsel = swz >> 7;               // 0..2 (block-uniform)
    const int rem  = swz & 127;
    const int bm   = rem >> 3;
    const int bnl  = rem & 7;
    const int isbf = flag[0];
    const bf16* Bp;
    void* Cp;
    int mode;
    if (wsel == 0)      { Bp = isbf ? (const bf16*)WqR : Wq_s; Cp = qbuf;  mode = 1; }
    else if (wsel == 1) { Bp = isbf ? (const bf16*)WkR : Wk_s; Cp = kbuf;  mode = 2; }
    else                { Bp = isbf ? (const bf16*)WvR : Wv_s; Cp = vtbuf; mode = 3; }
    gemm_core256<256>(A, Bp, Cp, 2048, bm, bnl, flag, fcos, fsin, mode, lds);
}

// Final GEMM: 256x128 tiles -> grid (16,16) = 256 blocks = exactly one full
// machine round (vs 128 blocks = half idle with 256x256). XCD swizzle.
__global__ __launch_bounds__(512, 2) void gemm128_fin(const bf16* __restrict__ A,
                                                      const bf16* __restrict__ Wo_s,
                                                      const void* __restrict__ WoR,
                                                      void* __restrict__ C,
                                                      const int* __restrict__ flag) {
    extern __shared__ char lds[];
    const int flat = blockIdx.y * 16 + blockIdx.x;
    const int swz  = (flat & 7) * 32 + (flat >> 3);
    const int bm   = swz >> 4;
    const int bnl  = swz & 15;
    const bf16* Bp = flag[0] ? (const bf16*)WoR : Wo_s;
    gemm_core256<128>(A, Bp, C, 2048, bm, bnl, flag, nullptr, nullptr, 4, lds);
}

// ---------------------------------------------------------------------------
__global__ void lambda_kernel(const void* lq1, const void* lq2,
                              const void* lk1, const void* lk2,
                              float* out, const int* __restrict__ flag) {
    const int isbf = flag[0];
    const int t = threadIdx.x;
    float p1 = loadf(lq1, t, isbf) * loadf(lk1, t, isbf);
    float p2 = loadf(lq2, t, isbf) * loadf(lk2, t, isbf);
#pragma unroll
    for (int m = 32; m > 0; m >>= 1) {
        p1 += __shfl_xor(p1, m);
        p2 += __shfl_xor(p2, m);
    }
    if (t == 0) out[0] = expf(p1) - expf(p2) + LAMBDA_INIT_F;
}

// ---------------------------------------------------------------------------
// Differential flash attention, paired-tile blocks, max-free softmax
// (r7-verified). XCD-aware block swizzle.
// grid = 512 blocks; block does q-tiles p and 31-p (33 iters).
// ---------------------------------------------------------------------------
__global__ __launch_bounds__(256) void diff_attn(const bf16* __restrict__ Q,
                                                 const bf16* __restrict__ K,
                                                 const bf16* __restrict__ Vt,
                                                 bf16* __restrict__ ctx,
                                                 const float* __restrict__ lam,
                                                 const void* __restrict__ norm_w,
                                                 const int* __restrict__ flag) {
    __shared__ __align__(16) char smem[55296];
    bf16* K1s = (bf16*)smem;                 // 64 keys x 64 dims  (8 KB) swizzled
    bf16* K2s = (bf16*)(smem + 8192);        // 8 KB swizzled
    bf16* Vs  = (bf16*)(smem + 16384);       // 128 dims x 64 keys (16 KB) swizzled
    char* pool = smem + 32768;               // 22528 B: Q staging / P1,P2

    const int isbf = flag[0];
    const int tid  = threadIdx.x;
    const int lane = tid & 63;
    const int quad = lane >> 4;
    const int l16  = lane & 15;
    const int w    = tid >> 6;
    const int t7   = l16 & 7;

    const int bidx = blockIdx.x;
    const int c8   = bidx & 7;               // presumed XCD (round-robin)
    const int r6   = bidx >> 3;
    const int p    = r6 & 15;                // pair id: tiles p and 31-p
    const int grp  = (r6 >> 4) * 8 + c8;     // (b,h) group; 4 groups per XCD
    const int h    = grp & 15;
    const int b    = grp >> 4;

    const float lambda_full = lam[0];
    float nw[8];
#pragma unroll
    for (int j = 0; j < 8; ++j) nw[j] = loadf(norm_w, j * 16 + l16, isbf);

    // P staging: per-wave 16 rows x stride 88 bf16 (176 B)
    bf16* P1s = (bf16*)(pool + w * 2816);
    bf16* P2s = (bf16*)(pool + 11264 + w * 2816);

    for (int tsel = 0; tsel < 2; ++tsel) {
        const int qt = tsel ? (31 - p) : p;
        const int q0 = qt * 64;

        __syncthreads();   // pool (P region of prev tile) free for Q staging

        // ---- Q staging via async16, swizzled; both heads (16 KB of pool) ----
#pragma unroll
        for (int i = 0; i < 2; ++i) {
            const int c = i * 256 + tid;     // 512 chunks (64 rows x 8)
            const int row = c >> 3, cc = c & 7;
            const int inner = cc ^ (row & 7);
            async16(Q + ((size_t)(b * 2048 + q0 + row) * 32 + 2 * h) * 64 + inner * 8,
                    pool + c * 16);
            async16(Q + ((size_t)(b * 2048 + q0 + row) * 32 + 2 * h + 1) * 64 + inner * 8,
                    pool + 8192 + c * 16);
        }
        __syncthreads();

        short8 qf1[2], qf2[2];
        {
            const int rho = w * 16 + l16;    // rho&7 == t7
#pragma unroll
            for (int c = 0; c < 2; ++c) {
                const int ch = (c * 4 + quad) ^ t7;
                qf1[c] = *(const short8*)(pool + rho * 128 + ch * 16);
                qf2[c] = *(const short8*)(pool + 8192 + rho * 128 + ch * 16);
            }
        }

        floatx4 O1[8], O2[8];
#pragma unroll
        for (int j = 0; j < 8; ++j)
#pragma unroll
            for (int r = 0; r < 4; ++r) { O1[j][r] = 0.0f; O2[j][r] = 0.0f; }
        float lp1[4] = {0.f, 0.f, 0.f, 0.f};
        float lp2[4] = {0.f, 0.f, 0.f, 0.f};

        for (int kt0 = 0; kt0 <= q0; kt0 += 64) {
            __syncthreads();   // (A) prev iter's LDS reads done
#pragma unroll
            for (int i = 0; i < 2; ++i) {
                const int c = i * 256 + tid;
                const int row = c >> 3, cc = c & 7;
                const int inner = cc ^ (row & 7);
                async16(K + ((size_t)(b * 2048 + kt0 + row) * 32 + 2 * h) * 64 + inner * 8,
                        (char*)K1s + c * 16);
                async16(K + ((size_t)(b * 2048 + kt0 + row) * 32 + 2 * h + 1) * 64 + inner * 8,
                        (char*)K2s + c * 16);
            }
#pragma unroll
            for (int i = 0; i < 4; ++i) {
                const int c = i * 256 + tid;     // 1024 chunks (128 dims x 8)
                const int d = c >> 3, cc = c & 7;
                const int inner = cc ^ (d & 7);
                async16(Vt + ((size_t)(b * 16 + h) * 128 + d) * 2048 + kt0 + inner * 8,
                        (char*)Vs + c * 16);
            }
            __syncthreads();   // (B) staging visible

            // ---- scores: wave's 16 q-rows x 64 keys, both heads ----
            floatx4 s1[4], s2[4];
#pragma unroll
            for (int j = 0; j < 4; ++j)
#pragma unroll
                for (int r = 0; r < 4; ++r) { s1[j][r] = 0.0f; s2[j][r] = 0.0f; }
#pragma unroll
            for (int c = 0; c < 2; ++c) {
                const int ch = ((c * 4 + quad) ^ t7) * 16;
#pragma unroll
                for (int j = 0; j < 4; ++j) {
                    short8 k1f = *(const short8*)((const char*)K1s + (j * 16 + l16) * 128 + ch);
                    s1[j] = MFMA16(qf1[c], k1f, s1[j]);
                    short8 k2f = *(const short8*)((const char*)K2s + (j * 16 + l16) * 128 + ch);
                    s2[j] = MFMA16(qf2[c], k2f, s2[j]);
                }
            }

            if (kt0 == q0) {   // diagonal tile mask
#pragma unroll
                for (int j = 0; j < 4; ++j)
#pragma unroll
                    for (int r = 0; r < 4; ++r)
                        if (j * 16 + l16 > w * 16 + quad * 4 + r) {
                            s1[j][r] = -1e30f;
                            s2[j][r] = -1e30f;
                        }
            }

            // ---- exp + per-lane row-sum partials + P write (no shuffles) ----
#pragma unroll
            for (int j = 0; j < 4; ++j)
#pragma unroll
                for (int r = 0; r < 4; ++r) {
                    const float e1 = __expf(s1[j][r]);
                    const float e2 = __expf(s2[j][r]);
                    lp1[r] += e1;
                    lp2[r] += e2;
                    P1s[(quad * 4 + r) * 88 + j * 16 + l16] = __float2bfloat16(e1);
                    P2s[(quad * 4 + r) * 88 + j * 16 + l16] = __float2bfloat16(e2);
                }
            // P is per-wave-private: same-wave ds ordering suffices, no barrier.

            // ---- PV: O[16 x 128] += P @ V ----
#pragma unroll
            for (int c = 0; c < 2; ++c) {
                short8 a1 = *(const short8*)((const char*)P1s + l16 * 176 + c * 64 + quad * 16);
                short8 a2 = *(const short8*)((const char*)P2s + l16 * 176 + c * 64 + quad * 16);
                const int ch = ((c * 4 + quad) ^ t7) * 16;
#pragma unroll
                for (int j = 0; j < 8; ++j) {
                    short8 vb = *(const short8*)((const char*)Vs + (j * 16 + l16) * 128 + ch);
                    O1[j] = MFMA16(a1, vb, O1[j]);
                    O2[j] = MFMA16(a2, vb, O2[j]);
                }
            }
        }

        // ---- epilogue: reduce row sums once, diff, RMSNorm, norm_w, store ----
#pragma unroll
        for (int r = 0; r < 4; ++r) {
            float t1 = lp1[r], t2 = lp2[r];
            t1 += __shfl_xor(t1, 1); t2 += __shfl_xor(t2, 1);
            t1 += __shfl_xor(t1, 2); t2 += __shfl_xor(t2, 2);
            t1 += __shfl_xor(t1, 4); t2 += __shfl_xor(t2, 4);
            t1 += __shfl_xor(t1, 8); t2 += __shfl_xor(t2, 8);
            const float i1 = 1.0f / t1;
            const float i2 = lambda_full / t2;
            float cv[8];
            float ss = 0.0f;
#pragma unroll
            for (int j = 0; j < 8; ++j) {
                const float v = O1[j][r] * i1 - O2[j][r] * i2;
                cv[j] = v;
                ss += v * v;
            }
            ss += __shfl_xor(ss, 1);
            ss += __shfl_xor(ss, 2);
            ss += __shfl_xor(ss, 4);
            ss += __shfl_xor(ss, 8);
            const float scale = rsqrtf(ss * (1.0f / 128.0f) + 1e-5f);
            const int row = q0 + w * 16 + quad * 4 + r;
            const size_t base = ((size_t)(b * 2048) + row) * 2048 + h * 128;
#pragma unroll
            for (int j = 0; j < 8; ++j)
                ctx[base + j * 16 + l16] = __float2bfloat16(cv[j] * scale * nw[j]);
        }
    }
}

// ---------------------------------------------------------------------------
extern "C" void kernel_launch(void* const* d_in, const int* in_sizes, int n_in,
                              void* d_out, int out_size, void* d_ws, size_t ws_size,
                              hipStream_t stream) {
    const void* x   = d_in[0];
    const void* Wq  = d_in[1];
    const void* Wk  = d_in[2];
    const void* Wv  = d_in[3];
    const void* Wo  = d_in[4];
    const void* lq1 = d_in[5];
    const void* lq2 = d_in[6];
    const void* lk1 = d_in[7];
    const void* lk2 = d_in[8];
    const void* nw  = d_in[9];
    const void* fc  = d_in[10];
    const void* fs  = d_in[11];

    const size_t BUF = (size_t)4096 * 2048 * sizeof(bf16);   // 16 MiB
    if (ws_size < 4 * BUF + 64) return;
    char* ws = (char*)d_ws;
    bf16*  qbuf  = (bf16*)(ws);
    bf16*  kbuf  = (bf16*)(ws + BUF);
    bf16*  vbuf  = (bf16*)(ws + 2 * BUF);    // xb, then ctxb (xb dead after QKV GEMM)
    bf16*  vtbuf = (bf16*)(ws + 3 * BUF);    // written directly by V part (mode 3)
    float* lamb  = (float*)(ws + 4 * BUF);
    int*   flag  = (int*)(ws + 4 * BUF + 8);
    bf16*  xb    = vbuf;
    bf16*  ctxb  = vbuf;

    // Weight staging for the f32 path: all three converted weights live in
    // d_out simultaneously (24 MiB <= 32 MiB f32 output; bf16 path skips
    // staging and reads the original tensors in place).
    bf16* wq_s = (bf16*)d_out;
    bf16* wk_s = wq_s + (size_t)2048 * 2048;
    bf16* wv_s = wk_s + (size_t)2048 * 2048;

    const int NW = 2048 * 2048;

    // allow dynamic LDS for the pipelined GEMMs (idempotent host calls)
    hipFuncSetAttribute(reinterpret_cast<const void*>(gemm256_qkv),
                        hipFuncAttributeMaxDynamicSharedMemorySize, 131072);
    hipFuncSetAttribute(reinterpret_cast<const void*>(gemm128_fin),
                        hipFuncAttributeMaxDynamicSharedMemorySize, 98304);

    detect_dtype<<<1, 64, 0, stream>>>((const unsigned short*)x, flag);
    convert_all<<<10240, 256, 0, stream>>>(x, Wq, Wk, Wv, xb, wq_s, wk_s, wv_s, flag);

    dim3 gq(24, 16);   // (3*2048)/256, 4096/256 — fused QKV
    gemm256_qkv<<<gq, 512, 131072, stream>>>(xb, wq_s, wk_s, wv_s, Wq, Wk, Wv,
                                             qbuf, kbuf, vtbuf, flag, fc, fs);

    lambda_kernel<<<1, 64, 0, stream>>>(lq1, lq2, lk1, lk2, lamb, flag);

    diff_attn<<<512, 256, 0, stream>>>(qbuf, kbuf, vtbuf, ctxb, lamb, nw, flag);

    // Wo conversion into qbuf (dead after attn); bf16 path reads Wo in place.
    to_bf16<<<NW / 2048, 256, 0, stream>>>(Wo, qbuf, NW, flag, 1);
    dim3 gf(16, 16);   // 2048/128, 4096/256 — one full machine round
    gemm128_fin<<<gf, 512, 98304, stream>>>(ctxb, qbuf, Wo, d_out, flag);
}